// Round 1
// baseline (555.971 us; speedup 1.0000x reference)
//
#include <hip/hip_runtime.h>

#define HW   16384   // 128*128
#define W_   128
#define H_   128
#define CC   64
#define BB   4

// ---------------------------------------------------------------------------
// K0: transpose w_align (o,c,k) -> wT (k,c,o) so phase-B weight reads are
// 16 consecutive floats at a wave-uniform address (s_load_dwordx8).
// ---------------------------------------------------------------------------
__global__ __launch_bounds__(256) void k_transpose_w(const float* __restrict__ w_align,
                                                     float* __restrict__ wT) {
    int i = blockIdx.x * 256 + threadIdx.x;   // i = o*576 + c*9 + k
    if (i >= CC * CC * 9) return;
    int o = i / 576;
    int r = i - o * 576;
    int c = r / 9;
    int k = r - c * 9;
    wT[(k * CC + c) * CC + o] = w_align[i];
}

// ---------------------------------------------------------------------------
// K1: 3x3 conv producing 27 offset/mask channels. One thread per pixel,
// 9 output channels per block-row (grid.y = 3 groups) for latency hiding.
// Mask channels (18..26) stored already as 2*sigmoid.
// ---------------------------------------------------------------------------
__global__ __launch_bounds__(256) void k_conv_off(const float* __restrict__ x,
                                                  const float* __restrict__ w_off,
                                                  const float* __restrict__ b_off,
                                                  float* __restrict__ off) {
    int idx = blockIdx.x * 256 + threadIdx.x;   // pixel id over B*HW
    int g   = blockIdx.y;                       // channel group: [9g, 9g+9)
    int b   = idx >> 14;
    int hw  = idx & (HW - 1);
    int h   = hw >> 7, wc = hw & 127;
    const float* xb = x + b * CC * HW;

    float acc[9];
#pragma unroll
    for (int o = 0; o < 9; o++) acc[o] = b_off[9 * g + o];

    for (int c = 0; c < CC; c++) {
        const float* xc = xb + c * HW;
        float v[9];
#pragma unroll
        for (int iy = 0; iy < 3; iy++) {
            int yy = h + iy - 1;
            int cy = min(max(yy, 0), 127);
#pragma unroll
            for (int ix = 0; ix < 3; ix++) {
                int xx = wc + ix - 1;
                int cx = min(max(xx, 0), 127);
                bool ok = ((unsigned)yy < 128u) && ((unsigned)xx < 128u);
                float vv = xc[cy * W_ + cx];      // clamped addr: always in-bounds
                v[iy * 3 + ix] = ok ? vv : 0.f;   // cndmask, no divergence
            }
        }
#pragma unroll
        for (int o = 0; o < 9; o++) {
            const float* wp = w_off + ((9 * g + o) * CC + c) * 9;  // wave-uniform -> s_load
#pragma unroll
            for (int t = 0; t < 9; t++) acc[o] = fmaf(wp[t], v[t], acc[o]);
        }
    }
#pragma unroll
    for (int o = 0; o < 9; o++) {
        int   oc  = 9 * g + o;
        float val = acc[o];
        if (g == 2) val = 2.f / (1.f + __expf(-val));   // mask = 2*sigmoid
        off[(b * 27 + oc) * HW + hw] = val;
    }
}

// ---------------------------------------------------------------------------
// K2 (hot): bilinear sampling + einsum + exp(sigmoid(.)) -> w tensor.
// Block = 256 threads = 4 waves, handles 64 consecutive pixels (one half-row).
// Per tap k: phase A stages S[c][p] = mask * bilinear(x[c], pos(p)) in LDS
// (wave wv covers channels [16wv,16wv+16) for its lane's pixel p=lane);
// phase B accumulates 16 outputs/thread with wave-uniform weight reads.
// ---------------------------------------------------------------------------
__global__ __launch_bounds__(256) void k_sample_gemm(const float* __restrict__ x,
                                                     const float* __restrict__ off,
                                                     const float* __restrict__ wT,
                                                     const float* __restrict__ b_align,
                                                     float* __restrict__ wten) {
    __shared__ float S[CC][64];   // [channel][pixel] : 16 KB
    int t    = threadIdx.x;
    int lane = t & 63;
    int wv   = t >> 6;
    int base = blockIdx.x * 64;          // global pixel base (same row: 64 | 128)
    int b    = base >> 14;
    int hw   = (base & (HW - 1)) + lane;
    int h    = hw >> 7, wc = hw & 127;
    const float* xb   = x + b * CC * HW;
    const float* offb = off + b * 27 * HW;

    float acc[16];
#pragma unroll
    for (int j = 0; j < 16; j++) acc[j] = 0.f;

    for (int k = 0; k < 9; k++) {
        // ---- phase A: sampling ----
        float dyv = offb[(2 * k) * HW + hw];
        float dxv = offb[(2 * k + 1) * HW + hw];
        float m   = offb[(18 + k) * HW + hw];
        float ys  = (float)h + (float)(k / 3 - 1) + dyv;
        float xs  = (float)wc + (float)(k % 3 - 1) + dxv;
        float y0f = floorf(ys), x0f = floorf(xs);
        float fy = ys - y0f, fx = xs - x0f;
        int y0 = (int)y0f, x0 = (int)x0f;
        int y1 = y0 + 1,   x1 = x0 + 1;
        bool vy0 = (unsigned)y0 < 128u, vy1 = (unsigned)y1 < 128u;
        bool vx0 = (unsigned)x0 < 128u, vx1 = (unsigned)x1 < 128u;
        int cy0 = min(max(y0, 0), 127), cy1 = min(max(y1, 0), 127);
        int cx0 = min(max(x0, 0), 127), cx1 = min(max(x1, 0), 127);
        int i00 = cy0 * W_ + cx0, i01 = cy0 * W_ + cx1;
        int i10 = cy1 * W_ + cx0, i11 = cy1 * W_ + cx1;
        float w00 = (1.f - fy) * (1.f - fx) * ((vy0 && vx0) ? m : 0.f);
        float w01 = (1.f - fy) * fx         * ((vy0 && vx1) ? m : 0.f);
        float w10 = fy * (1.f - fx)         * ((vy1 && vx0) ? m : 0.f);
        float w11 = fy * fx                 * ((vy1 && vx1) ? m : 0.f);

        if (k) __syncthreads();   // S from previous tap fully consumed
#pragma unroll
        for (int i = 0; i < 16; i++) {
            int c = wv * 16 + i;
            const float* xc = xb + c * HW;
            S[c][lane] = w00 * xc[i00] + w01 * xc[i01] + w10 * xc[i10] + w11 * xc[i11];
        }
        __syncthreads();

        // ---- phase B: einsum accumulation ----
        const float* wk = wT + k * CC * CC;        // [c][o]
        for (int c = 0; c < CC; c++) {
            float vc = S[c][lane];                 // stride-1: conflict-free
            const float* wrow = wk + c * CC + wv * 16;  // wave-uniform -> s_load x8
#pragma unroll
            for (int j = 0; j < 16; j++) acc[j] = fmaf(vc, wrow[j], acc[j]);
        }
    }

    // ---- epilogue: bias + exp(sigmoid) ----
    int obase = wv * 16;
    float* wb = wten + b * CC * HW;
#pragma unroll
    for (int j = 0; j < 16; j++) {
        float u  = acc[j] + b_align[obase + j];
        float sg = 1.f / (1.f + __expf(-u));
        wb[(obase + j) * HW + hw] = __expf(sg);
    }
}

// ---------------------------------------------------------------------------
// K3: out = avgpool3s2(w*x) / avgpool3s2(w). The /9 cancels; zero-padding
// contributes 0 to both sums, so only valid taps are summed.
// ---------------------------------------------------------------------------
__global__ __launch_bounds__(256) void k_pool(const float* __restrict__ x,
                                              const float* __restrict__ wten,
                                              float* __restrict__ out) {
    int idx = blockIdx.x * 256 + threadIdx.x;   // (b,c,oh,ow) over 4*64*64*64
    int ow = idx & 63;
    int oh = (idx >> 6) & 63;
    int bc = idx >> 12;                          // b*64 + c (matches x layout)
    const float* wp = wten + bc * HW;
    const float* xp = x + bc * HW;
    float num = 0.f, den = 0.f;
#pragma unroll
    for (int iy = 0; iy < 3; iy++) {
        int y = 2 * oh + iy - 1;
        if ((unsigned)y >= 128u) continue;
#pragma unroll
        for (int ix = 0; ix < 3; ix++) {
            int xcol = 2 * ow + ix - 1;
            if ((unsigned)xcol >= 128u) continue;
            float wv = wp[y * W_ + xcol];
            float xv = xp[y * W_ + xcol];
            num = fmaf(wv, xv, num);
            den += wv;
        }
    }
    out[idx] = num / den;
}

// ---------------------------------------------------------------------------
extern "C" void kernel_launch(void* const* d_in, const int* in_sizes, int n_in,
                              void* d_out, int out_size, void* d_ws, size_t ws_size,
                              hipStream_t stream) {
    const float* x       = (const float*)d_in[0];   // (4,64,128,128)
    const float* w_off   = (const float*)d_in[1];   // (27,64,3,3)
    const float* b_off   = (const float*)d_in[2];   // (27,)
    const float* w_align = (const float*)d_in[3];   // (64,64,3,3)
    const float* b_align = (const float*)d_in[4];   // (64,)
    float* out = (float*)d_out;                     // (4,64,64,64)

    // workspace layout (floats): off[4*27*HW] | wT[9*64*64] | wten[4*64*HW]
    float* off  = (float*)d_ws;
    float* wT   = off + BB * 27 * HW;
    float* wten = wT + 9 * CC * CC;

    k_transpose_w<<<dim3(144), dim3(256), 0, stream>>>(w_align, wT);
    k_conv_off<<<dim3(256, 3), dim3(256), 0, stream>>>(x, w_off, b_off, off);
    k_sample_gemm<<<dim3(1024), dim3(256), 0, stream>>>(x, off, wT, b_align, wten);
    k_pool<<<dim3(4096), dim3(256), 0, stream>>>(x, wten, out);
}

// Round 2
// 184.707 us; speedup vs baseline: 3.0100x; 3.0100x over previous
//
#include <hip/hip_runtime.h>
#include <hip/hip_bf16.h>

#define HW 16384   // 128*128
#define CC 64
#define BB 4

typedef __attribute__((ext_vector_type(8))) short bf8;   // 8 bf16 (4 VGPRs)
typedef __attribute__((ext_vector_type(4))) float f4;    // MFMA C/D frag

static __device__ __forceinline__ float bf2f(unsigned short u) {
    return __uint_as_float(((unsigned)u) << 16);
}
static __device__ __forceinline__ unsigned short f2bf(float f) {
    __hip_bfloat16 h = __float2bfloat16(f);   // RNE
    return *reinterpret_cast<unsigned short*>(&h);
}

// ---------------------------------------------------------------------------
// K0: weight prep.
//  wA  [32][576] bf16 : wA[m][t*64+c] = w_off[m][c][t]   (rows 27..31 zero)
//  Wal [64][576] bf16 : Wal[o][t*64+c] = w_align[o][c][t]
// Row-major, K'-contiguous -> A-fragment is one 16B load per lane.
// ---------------------------------------------------------------------------
__global__ __launch_bounds__(256) void k_prep(const float* __restrict__ w_off,
                                              const float* __restrict__ w_align,
                                              unsigned short* __restrict__ wA,
                                              unsigned short* __restrict__ Wal) {
    int i = blockIdx.x * 256 + threadIdx.x;
    if (i < 32 * 576) {
        int m = i / 576, r = i - m * 576, t = r >> 6, c = r & 63;
        float v = (m < 27) ? w_off[m * 576 + c * 9 + t] : 0.f;
        wA[i] = f2bf(v);
    } else {
        int j = i - 32 * 576;
        if (j < 64 * 576) {
            int o = j / 576, r = j - o * 576, t = r >> 6, c = r & 63;
            Wal[j] = f2bf(w_align[o * 576 + c * 9 + t]);
        }
    }
}

// ---------------------------------------------------------------------------
// K1: x (NCHW fp32) -> xT[b*HW+hw][c] bf16 (channels contiguous, 128B rows).
// ---------------------------------------------------------------------------
__global__ __launch_bounds__(256) void k_tx(const float* __restrict__ x,
                                            unsigned short* __restrict__ xT) {
    int idx = blockIdx.x * 256 + threadIdx.x;          // b*HW + hw
    const float* xp = x + (size_t)(idx >> 14) * CC * HW + (idx & (HW - 1));
    unsigned short* op = xT + (size_t)idx * CC;
#pragma unroll
    for (int c8 = 0; c8 < 8; c8++) {
        unsigned short u[8];
#pragma unroll
        for (int j = 0; j < 8; j++) u[j] = f2bf(xp[(size_t)(c8 * 8 + j) * HW]);
        uint4 q;
        q.x = u[0] | ((unsigned)u[1] << 16);
        q.y = u[2] | ((unsigned)u[3] << 16);
        q.z = u[4] | ((unsigned)u[5] << 16);
        q.w = u[6] | ((unsigned)u[7] << 16);
        *(uint4*)(op + c8 * 8) = q;
    }
}

// ---------------------------------------------------------------------------
// K2: offset conv as 9-tap shifted MFMA GEMM. M=32 (27 used), K=576, N=65536.
// Block = 4 waves x 16 pixels; per kstep: tap = s>>1, c-half = (s&1)*32.
// B-frag = xT row of the tap-shifted pixel (zeroed when out of image:
// conv has zero padding). Epilogue: +b_off, mask rows get 2*sigmoid.
// ---------------------------------------------------------------------------
__global__ __launch_bounds__(256) void k_conv(const unsigned short* __restrict__ xT,
                                              const unsigned short* __restrict__ wA,
                                              const float* __restrict__ b_off,
                                              float* __restrict__ off) {
    int t = threadIdx.x, lane = t & 63, wv = t >> 6;
    int quad = lane >> 4, col = lane & 15;
    int n = blockIdx.x * 64 + wv * 16 + col;           // global pixel
    int b = n >> 14, hw = n & (HW - 1), h = hw >> 7, w = hw & 127;
    const unsigned short* xTb = xT + (size_t)b * HW * CC;

    f4 acc0 = {0.f, 0.f, 0.f, 0.f};
    f4 acc1 = {0.f, 0.f, 0.f, 0.f};
    const bf8 zero = {0, 0, 0, 0, 0, 0, 0, 0};

    for (int s = 0; s < 18; s++) {
        int tap = s >> 1, c0 = (s & 1) << 5;
        int dyt = tap / 3 - 1, dxt = tap - (tap / 3) * 3 - 1;
        int hs = h + dyt, ws = w + dxt;
        bool valid = ((unsigned)hs < 128u) && ((unsigned)ws < 128u);
        int hc = min(max(hs, 0), 127), wc = min(max(ws, 0), 127);
        bf8 bfrag = *(const bf8*)(xTb + ((size_t)(hc * 128 + wc)) * CC + c0 + quad * 8);
        bfrag = valid ? bfrag : zero;
        bf8 a0 = *(const bf8*)(wA + (size_t)col * 576 + tap * 64 + c0 + quad * 8);
        bf8 a1 = *(const bf8*)(wA + (size_t)(col + 16) * 576 + tap * 64 + c0 + quad * 8);
        acc0 = __builtin_amdgcn_mfma_f32_16x16x32_bf16(a0, bfrag, acc0, 0, 0, 0);
        acc1 = __builtin_amdgcn_mfma_f32_16x16x32_bf16(a1, bfrag, acc1, 0, 0, 0);
    }
#pragma unroll
    for (int i = 0; i < 4; i++) {
        int o0 = quad * 4 + i;                          // 0..15, always < 27
        {
            float v = acc0[i] + b_off[o0];
            if (o0 >= 18) v = 2.f / (1.f + __expf(-v));
            off[((size_t)b * 27 + o0) * HW + hw] = v;
        }
        int o1 = 16 + o0;
        if (o1 < 27) {
            float v = acc1[i] + b_off[o1];
            if (o1 >= 18) v = 2.f / (1.f + __expf(-v));
            off[((size_t)b * 27 + o1) * HW + hw] = v;
        }
    }
}

// ---------------------------------------------------------------------------
// K3: sampler. Writes Sbuf[p_local][k*64+c] bf16 (= B-fragment layout).
// Wave = 8 pixels x 8 channel-groups; per (pix,tap,corner) ONE dwordx4 grabs
// 8 contiguous channels from xT. Low VGPR -> high occupancy hides gather lat.
// ---------------------------------------------------------------------------
__global__ __launch_bounds__(256) void k_sample(const unsigned short* __restrict__ xT,
                                                const float* __restrict__ off,
                                                unsigned short* __restrict__ Sbuf,
                                                int pix0) {
    int t = threadIdx.x, lane = t & 63, wv = t >> 6;
    int cg = lane & 7;                                  // channel group (8 ch)
    int pl = blockIdx.x * 32 + wv * 8 + (lane >> 3);    // chunk-local pixel
    int pg = pix0 + pl;                                 // global pixel
    int b = pg >> 14, hw = pg & (HW - 1), h = hw >> 7, w = hw & 127;
    const unsigned short* xTb = xT + (size_t)b * HW * CC;
    const float* offb = off + (size_t)b * 27 * HW;
    unsigned short* srow = Sbuf + (size_t)pl * 576;

    for (int k = 0; k < 9; k++) {
        float dy = offb[(2 * k) * HW + hw];
        float dx = offb[(2 * k + 1) * HW + hw];
        float m  = offb[(18 + k) * HW + hw];
        int k3 = k / 3;
        float ys = (float)(h + k3 - 1) + dy;
        float xs = (float)(w + (k - 3 * k3) - 1) + dx;
        float y0f = floorf(ys), x0f = floorf(xs);
        float fy = ys - y0f, fx = xs - x0f;
        int y0 = (int)y0f, x0 = (int)x0f;
        int y1 = y0 + 1, x1 = x0 + 1;
        bool vy0 = (unsigned)y0 < 128u, vy1 = (unsigned)y1 < 128u;
        bool vx0 = (unsigned)x0 < 128u, vx1 = (unsigned)x1 < 128u;
        int cy0 = min(max(y0, 0), 127), cy1 = min(max(y1, 0), 127);
        int cx0 = min(max(x0, 0), 127), cx1 = min(max(x1, 0), 127);
        float w00 = (1.f - fy) * (1.f - fx) * ((vy0 && vx0) ? m : 0.f);
        float w01 = (1.f - fy) * fx         * ((vy0 && vx1) ? m : 0.f);
        float w10 = fy * (1.f - fx)         * ((vy1 && vx0) ? m : 0.f);
        float w11 = fy * fx                 * ((vy1 && vx1) ? m : 0.f);

        const uint4 q00 = *(const uint4*)(xTb + ((size_t)(cy0 * 128 + cx0)) * CC + cg * 8);
        const uint4 q01 = *(const uint4*)(xTb + ((size_t)(cy0 * 128 + cx1)) * CC + cg * 8);
        const uint4 q10 = *(const uint4*)(xTb + ((size_t)(cy1 * 128 + cx0)) * CC + cg * 8);
        const uint4 q11 = *(const uint4*)(xTb + ((size_t)(cy1 * 128 + cx1)) * CC + cg * 8);
        const unsigned short* u00 = (const unsigned short*)&q00;
        const unsigned short* u01 = (const unsigned short*)&q01;
        const unsigned short* u10 = (const unsigned short*)&q10;
        const unsigned short* u11 = (const unsigned short*)&q11;
        unsigned short ov[8];
#pragma unroll
        for (int j = 0; j < 8; j++) {
            float v = w00 * bf2f(u00[j]) + w01 * bf2f(u01[j])
                    + w10 * bf2f(u10[j]) + w11 * bf2f(u11[j]);
            ov[j] = f2bf(v);
        }
        uint4 q;
        q.x = ov[0] | ((unsigned)ov[1] << 16);
        q.y = ov[2] | ((unsigned)ov[3] << 16);
        q.z = ov[4] | ((unsigned)ov[5] << 16);
        q.w = ov[6] | ((unsigned)ov[7] << 16);
        *(uint4*)(srow + k * 64 + cg * 8) = q;
    }
}

// ---------------------------------------------------------------------------
// K4: align einsum as MFMA GEMM. M=64, K=576, N=chunk pixels.
// Wave = 16 pixels x full M (4 m-tiles). Epilogue: +b_align, exp(sigmoid).
// ---------------------------------------------------------------------------
__global__ __launch_bounds__(256) void k_gemm(const unsigned short* __restrict__ Sbuf,
                                              const unsigned short* __restrict__ Wal,
                                              const float* __restrict__ b_align,
                                              float* __restrict__ wten,
                                              int pix0) {
    int t = threadIdx.x, lane = t & 63, wv = t >> 6;
    int quad = lane >> 4, col = lane & 15;
    int pl = blockIdx.x * 64 + wv * 16 + col;           // chunk-local pixel
    int pg = pix0 + pl;
    int b = pg >> 14, hw = pg & (HW - 1);

    f4 acc[4];
#pragma unroll
    for (int mt = 0; mt < 4; mt++) acc[mt] = (f4){0.f, 0.f, 0.f, 0.f};

    const unsigned short* srow = Sbuf + (size_t)pl * 576 + quad * 8;
    const unsigned short* wrow = Wal + (size_t)col * 576 + quad * 8;
    for (int s = 0; s < 18; s++) {
        bf8 bfrag = *(const bf8*)(srow + s * 32);
#pragma unroll
        for (int mt = 0; mt < 4; mt++) {
            bf8 a = *(const bf8*)(wrow + (size_t)(mt * 16) * 576 + s * 32);
            acc[mt] = __builtin_amdgcn_mfma_f32_16x16x32_bf16(a, bfrag, acc[mt], 0, 0, 0);
        }
    }
#pragma unroll
    for (int mt = 0; mt < 4; mt++)
#pragma unroll
        for (int i = 0; i < 4; i++) {
            int o = mt * 16 + quad * 4 + i;
            float u = acc[mt][i] + b_align[o];
            float sg = 1.f / (1.f + __expf(-u));
            wten[((size_t)b * CC + o) * HW + hw] = __expf(sg);
        }
}

// ---------------------------------------------------------------------------
// K5: out = pool3s2(w*x)/pool3s2(w) (the /9 cancels; zero-pad taps drop out).
// ---------------------------------------------------------------------------
__global__ __launch_bounds__(256) void k_pool(const float* __restrict__ x,
                                              const float* __restrict__ wten,
                                              float* __restrict__ out) {
    int idx = blockIdx.x * 256 + threadIdx.x;
    int ow = idx & 63;
    int oh = (idx >> 6) & 63;
    int bc = idx >> 12;
    const float* wp = wten + (size_t)bc * HW;
    const float* xp = x + (size_t)bc * HW;
    float num = 0.f, den = 0.f;
#pragma unroll
    for (int iy = 0; iy < 3; iy++) {
        int y = 2 * oh + iy - 1;
        if ((unsigned)y >= 128u) continue;
#pragma unroll
        for (int ix = 0; ix < 3; ix++) {
            int xc = 2 * ow + ix - 1;
            if ((unsigned)xc >= 128u) continue;
            float wv = wp[y * 128 + xc];
            float xv = xp[y * 128 + xc];
            num = fmaf(wv, xv, num);
            den += wv;
        }
    }
    out[idx] = num / den;
}

// ---------------------------------------------------------------------------
extern "C" void kernel_launch(void* const* d_in, const int* in_sizes, int n_in,
                              void* d_out, int out_size, void* d_ws, size_t ws_size,
                              hipStream_t stream) {
    const float* x       = (const float*)d_in[0];
    const float* w_off   = (const float*)d_in[1];
    const float* b_off   = (const float*)d_in[2];
    const float* w_align = (const float*)d_in[3];
    const float* b_align = (const float*)d_in[4];
    float* out = (float*)d_out;

    // workspace layout (~70.1 MB):
    char* p = (char*)d_ws;
    float* off  = (float*)p;                 p += (size_t)BB * 27 * HW * 4;   // 7.08 MB
    float* wten = (float*)p;                 p += (size_t)BB * CC * HW * 4;   // 16.78 MB
    unsigned short* xT  = (unsigned short*)p; p += (size_t)BB * HW * CC * 2;  // 8.39 MB
    unsigned short* wA  = (unsigned short*)p; p += 32 * 576 * 2;              // 36.9 KB
    unsigned short* Wal = (unsigned short*)p; p += 64 * 576 * 2;              // 73.7 KB
    unsigned short* Sbuf = (unsigned short*)p;                                // 37.75 MB

    k_prep<<<dim3(216), dim3(256), 0, stream>>>(w_off, w_align, wA, Wal);
    k_tx<<<dim3(256), dim3(256), 0, stream>>>(x, xT);
    k_conv<<<dim3(1024), dim3(256), 0, stream>>>(xT, wA, b_off, off);
    for (int chunk = 0; chunk < 2; chunk++) {
        int pix0 = chunk * 32768;   // 2 batches per chunk
        k_sample<<<dim3(1024), dim3(256), 0, stream>>>(xT, off, Sbuf, pix0);
        k_gemm<<<dim3(512), dim3(256), 0, stream>>>(Sbuf, Wal, b_align, wten, pix0);
    }
    k_pool<<<dim3(4096), dim3(256), 0, stream>>>(x, wten, out);
}

// Round 3
// 158.228 us; speedup vs baseline: 3.5137x; 1.1673x over previous
//
#include <hip/hip_runtime.h>
#include <hip/hip_bf16.h>

#define HW 16384   // 128*128
#define CC 64
#define BB 4

typedef __attribute__((ext_vector_type(8))) short bf8;   // 8 bf16 (4 VGPRs)
typedef __attribute__((ext_vector_type(4))) float f4;    // MFMA C/D frag

static __device__ __forceinline__ float bf2f(unsigned short u) {
    return __uint_as_float(((unsigned)u) << 16);
}
static __device__ __forceinline__ unsigned short f2bf(float f) {
    __hip_bfloat16 h = __float2bfloat16(f);   // RNE
    return *reinterpret_cast<unsigned short*>(&h);
}

// ---------------------------------------------------------------------------
// K0: weight prep.
//  wA  [32][576] bf16 : wA[m][t*64+c] = w_off[m][c][t]   (rows 27..31 zero)
//  Wal [64][576] bf16 : Wal[o][t*64+c] = w_align[o][c][t]
// ---------------------------------------------------------------------------
__global__ __launch_bounds__(256) void k_prep(const float* __restrict__ w_off,
                                              const float* __restrict__ w_align,
                                              unsigned short* __restrict__ wA,
                                              unsigned short* __restrict__ Wal) {
    int i = blockIdx.x * 256 + threadIdx.x;
    if (i < 32 * 576) {
        int m = i / 576, r = i - m * 576, t = r >> 6, c = r & 63;
        float v = (m < 27) ? w_off[m * 576 + c * 9 + t] : 0.f;
        wA[i] = f2bf(v);
    } else {
        int j = i - 32 * 576;
        if (j < 64 * 576) {
            int o = j / 576, r = j - o * 576, t = r >> 6, c = r & 63;
            Wal[j] = f2bf(w_align[o * 576 + c * 9 + t]);
        }
    }
}

// ---------------------------------------------------------------------------
// K1: x (NCHW fp32) -> xT[b*HW+hw][c] bf16 (channels contiguous, 128B rows).
// ---------------------------------------------------------------------------
__global__ __launch_bounds__(256) void k_tx(const float* __restrict__ x,
                                            unsigned short* __restrict__ xT) {
    int idx = blockIdx.x * 256 + threadIdx.x;          // b*HW + hw
    const float* xp = x + (size_t)(idx >> 14) * CC * HW + (idx & (HW - 1));
    unsigned short* op = xT + (size_t)idx * CC;
#pragma unroll
    for (int c8 = 0; c8 < 8; c8++) {
        unsigned short u[8];
#pragma unroll
        for (int j = 0; j < 8; j++) u[j] = f2bf(xp[(size_t)(c8 * 8 + j) * HW]);
        uint4 q;
        q.x = u[0] | ((unsigned)u[1] << 16);
        q.y = u[2] | ((unsigned)u[3] << 16);
        q.z = u[4] | ((unsigned)u[5] << 16);
        q.w = u[6] | ((unsigned)u[7] << 16);
        *(uint4*)(op + c8 * 8) = q;
    }
}

// ---------------------------------------------------------------------------
// K2: offset conv as 9-tap shifted MFMA GEMM. M=32 (27 used), K=576, N=65536.
// ---------------------------------------------------------------------------
__global__ __launch_bounds__(256) void k_conv(const unsigned short* __restrict__ xT,
                                              const unsigned short* __restrict__ wA,
                                              const float* __restrict__ b_off,
                                              float* __restrict__ off) {
    int t = threadIdx.x, lane = t & 63, wv = t >> 6;
    int quad = lane >> 4, col = lane & 15;
    int n = blockIdx.x * 64 + wv * 16 + col;           // global pixel
    int b = n >> 14, hw = n & (HW - 1), h = hw >> 7, w = hw & 127;
    const unsigned short* xTb = xT + (size_t)b * HW * CC;

    f4 acc0 = {0.f, 0.f, 0.f, 0.f};
    f4 acc1 = {0.f, 0.f, 0.f, 0.f};
    const bf8 zero = {0, 0, 0, 0, 0, 0, 0, 0};

    for (int s = 0; s < 18; s++) {
        int tap = s >> 1, c0 = (s & 1) << 5;
        int dyt = tap / 3 - 1, dxt = tap - (tap / 3) * 3 - 1;
        int hs = h + dyt, ws = w + dxt;
        bool valid = ((unsigned)hs < 128u) && ((unsigned)ws < 128u);
        int hc = min(max(hs, 0), 127), wc = min(max(ws, 0), 127);
        bf8 bfrag = *(const bf8*)(xTb + ((size_t)(hc * 128 + wc)) * CC + c0 + quad * 8);
        bfrag = valid ? bfrag : zero;
        bf8 a0 = *(const bf8*)(wA + (size_t)col * 576 + tap * 64 + c0 + quad * 8);
        bf8 a1 = *(const bf8*)(wA + (size_t)(col + 16) * 576 + tap * 64 + c0 + quad * 8);
        acc0 = __builtin_amdgcn_mfma_f32_16x16x32_bf16(a0, bfrag, acc0, 0, 0, 0);
        acc1 = __builtin_amdgcn_mfma_f32_16x16x32_bf16(a1, bfrag, acc1, 0, 0, 0);
    }
#pragma unroll
    for (int i = 0; i < 4; i++) {
        int o0 = quad * 4 + i;                          // 0..15, always < 27
        {
            float v = acc0[i] + b_off[o0];
            if (o0 >= 18) v = 2.f / (1.f + __expf(-v));
            off[((size_t)b * 27 + o0) * HW + hw] = v;
        }
        int o1 = 16 + o0;
        if (o1 < 27) {
            float v = acc1[i] + b_off[o1];
            if (o1 >= 18) v = 2.f / (1.f + __expf(-v));
            off[((size_t)b * 27 + o1) * HW + hw] = v;
        }
    }
}

// ---------------------------------------------------------------------------
// K3 (fused): sampling -> LDS -> einsum MFMA -> exp(sigmoid) -> wten.
// Block = 256 threads / 32 pixels.
//  Phase A: thread (p = wv*8+(lane>>3), cg = lane&7) samples channels
//           [8cg,8cg+8) for tap k, stores 16B at S2[((k*8+cg)*32+p)*8].
//           bank = 4p mod 32 -> 8 dwords/bank (structural minimum, no conflict)
//  Phase B: wave wv = (pg = wv&1, mh = wv>>1): 16 pixels x 32 outputs.
//           B-frag read S2[((k*8 + (s&1)*4+quad)*32 + pg*16+col)*8]:
//           bank = 4col mod 32 -> 8 dwords/bank, conflict-free.
// Offsets staged once per block into LDS (kills 8x redundant reads).
// ---------------------------------------------------------------------------
__global__ __launch_bounds__(256) void k_fused(const unsigned short* __restrict__ xT,
                                               const float* __restrict__ off,
                                               const unsigned short* __restrict__ Wal,
                                               const float* __restrict__ b_align,
                                               float* __restrict__ wten) {
    __shared__ unsigned short S2[2304 * 8];   // 36864 B
    __shared__ float offL[27][32];            // 3456 B

    int t = threadIdx.x, lane = t & 63, wv = t >> 6;
    int n0 = blockIdx.x * 32;                 // global pixel base
    int b = n0 >> 14, hw0 = n0 & (HW - 1);
    const unsigned short* xTb = xT + (size_t)b * HW * CC;

    // ---- stage offsets ----
    for (int i = t; i < 27 * 32; i += 256) {
        int r = i >> 5, p = i & 31;
        offL[r][p] = off[((size_t)b * 27 + r) * HW + hw0 + p];
    }
    __syncthreads();

    // ---- phase A: sampling into LDS ----
    {
        int cg = lane & 7;
        int p  = wv * 8 + (lane >> 3);
        int hw = hw0 + p, h = hw >> 7, w = hw & 127;
#pragma unroll
        for (int k = 0; k < 9; k++) {
            float dy = offL[2 * k][p];
            float dx = offL[2 * k + 1][p];
            float m  = offL[18 + k][p];
            int k3 = k / 3;
            float ys = (float)(h + k3 - 1) + dy;
            float xs = (float)(w + (k - 3 * k3) - 1) + dx;
            float y0f = floorf(ys), x0f = floorf(xs);
            float fy = ys - y0f, fx = xs - x0f;
            int y0 = (int)y0f, x0 = (int)x0f;
            int y1 = y0 + 1, x1 = x0 + 1;
            bool vy0 = (unsigned)y0 < 128u, vy1 = (unsigned)y1 < 128u;
            bool vx0 = (unsigned)x0 < 128u, vx1 = (unsigned)x1 < 128u;
            int cy0 = min(max(y0, 0), 127), cy1 = min(max(y1, 0), 127);
            int cx0 = min(max(x0, 0), 127), cx1 = min(max(x1, 0), 127);
            float w00 = (1.f - fy) * (1.f - fx) * ((vy0 && vx0) ? m : 0.f);
            float w01 = (1.f - fy) * fx         * ((vy0 && vx1) ? m : 0.f);
            float w10 = fy * (1.f - fx)         * ((vy1 && vx0) ? m : 0.f);
            float w11 = fy * fx                 * ((vy1 && vx1) ? m : 0.f);

            const uint4 q00 = *(const uint4*)(xTb + ((size_t)(cy0 * 128 + cx0)) * CC + cg * 8);
            const uint4 q01 = *(const uint4*)(xTb + ((size_t)(cy0 * 128 + cx1)) * CC + cg * 8);
            const uint4 q10 = *(const uint4*)(xTb + ((size_t)(cy1 * 128 + cx0)) * CC + cg * 8);
            const uint4 q11 = *(const uint4*)(xTb + ((size_t)(cy1 * 128 + cx1)) * CC + cg * 8);
            const unsigned short* u00 = (const unsigned short*)&q00;
            const unsigned short* u01 = (const unsigned short*)&q01;
            const unsigned short* u10 = (const unsigned short*)&q10;
            const unsigned short* u11 = (const unsigned short*)&q11;
            unsigned short ov[8];
#pragma unroll
            for (int j = 0; j < 8; j++) {
                float v = w00 * bf2f(u00[j]) + w01 * bf2f(u01[j])
                        + w10 * bf2f(u10[j]) + w11 * bf2f(u11[j]);
                ov[j] = f2bf(v);
            }
            uint4 q;
            q.x = ov[0] | ((unsigned)ov[1] << 16);
            q.y = ov[2] | ((unsigned)ov[3] << 16);
            q.z = ov[4] | ((unsigned)ov[5] << 16);
            q.w = ov[6] | ((unsigned)ov[7] << 16);
            *(uint4*)(S2 + ((size_t)((k * 8 + cg) * 32 + p)) * 8) = q;
        }
    }
    __syncthreads();

    // ---- phase B: einsum MFMA ----
    {
        int quad = lane >> 4, col = lane & 15;
        int pg = wv & 1, mh = wv >> 1;
        int pp = pg * 16 + col;
        f4 acc0 = {0.f, 0.f, 0.f, 0.f};
        f4 acc1 = {0.f, 0.f, 0.f, 0.f};
        const unsigned short* wrow = Wal + (size_t)(mh * 32 + col) * 576 + quad * 8;
#pragma unroll
        for (int s = 0; s < 18; s++) {
            int k = s >> 1, cgc = ((s & 1) << 2) + quad;
            bf8 bfrag = *(const bf8*)(S2 + ((size_t)((k * 8 + cgc) * 32 + pp)) * 8);
            bf8 a0 = *(const bf8*)(wrow + s * 32);
            bf8 a1 = *(const bf8*)(wrow + (size_t)16 * 576 + s * 32);
            acc0 = __builtin_amdgcn_mfma_f32_16x16x32_bf16(a0, bfrag, acc0, 0, 0, 0);
            acc1 = __builtin_amdgcn_mfma_f32_16x16x32_bf16(a1, bfrag, acc1, 0, 0, 0);
        }
#pragma unroll
        for (int i = 0; i < 4; i++) {
            {
                int o = mh * 32 + quad * 4 + i;
                float u = acc0[i] + b_align[o];
                float sg = 1.f / (1.f + __expf(-u));
                wten[((size_t)b * CC + o) * HW + hw0 + pp] = __expf(sg);
            }
            {
                int o = mh * 32 + 16 + quad * 4 + i;
                float u = acc1[i] + b_align[o];
                float sg = 1.f / (1.f + __expf(-u));
                wten[((size_t)b * CC + o) * HW + hw0 + pp] = __expf(sg);
            }
        }
    }
}

// ---------------------------------------------------------------------------
// K4: out = pool3s2(w*x)/pool3s2(w) (the /9 cancels; zero-pad taps drop out).
// ---------------------------------------------------------------------------
__global__ __launch_bounds__(256) void k_pool(const float* __restrict__ x,
                                              const float* __restrict__ wten,
                                              float* __restrict__ out) {
    int idx = blockIdx.x * 256 + threadIdx.x;
    int ow = idx & 63;
    int oh = (idx >> 6) & 63;
    int bc = idx >> 12;
    const float* wp = wten + (size_t)bc * HW;
    const float* xp = x + (size_t)bc * HW;
    float num = 0.f, den = 0.f;
#pragma unroll
    for (int iy = 0; iy < 3; iy++) {
        int y = 2 * oh + iy - 1;
        if ((unsigned)y >= 128u) continue;
#pragma unroll
        for (int ix = 0; ix < 3; ix++) {
            int xc = 2 * ow + ix - 1;
            if ((unsigned)xc >= 128u) continue;
            float wv = wp[y * 128 + xc];
            float xv = xp[y * 128 + xc];
            num = fmaf(wv, xv, num);
            den += wv;
        }
    }
    out[idx] = num / den;
}

// ---------------------------------------------------------------------------
extern "C" void kernel_launch(void* const* d_in, const int* in_sizes, int n_in,
                              void* d_out, int out_size, void* d_ws, size_t ws_size,
                              hipStream_t stream) {
    const float* x       = (const float*)d_in[0];
    const float* w_off   = (const float*)d_in[1];
    const float* b_off   = (const float*)d_in[2];
    const float* w_align = (const float*)d_in[3];
    const float* b_align = (const float*)d_in[4];
    float* out = (float*)d_out;

    // workspace layout (~32.4 MB):
    char* p = (char*)d_ws;
    float* off  = (float*)p;                  p += (size_t)BB * 27 * HW * 4;  // 7.08 MB
    float* wten = (float*)p;                  p += (size_t)BB * CC * HW * 4;  // 16.78 MB
    unsigned short* xT  = (unsigned short*)p; p += (size_t)BB * HW * CC * 2;  // 8.39 MB
    unsigned short* wA  = (unsigned short*)p; p += 32 * 576 * 2;              // 36.9 KB
    unsigned short* Wal = (unsigned short*)p;                                 // 73.7 KB

    k_prep<<<dim3(216), dim3(256), 0, stream>>>(w_off, w_align, wA, Wal);
    k_tx<<<dim3(256), dim3(256), 0, stream>>>(x, xT);
    k_conv<<<dim3(1024), dim3(256), 0, stream>>>(xT, wA, b_off, off);
    k_fused<<<dim3(2048), dim3(256), 0, stream>>>(xT, off, Wal, b_align, wten);
    k_pool<<<dim3(4096), dim3(256), 0, stream>>>(x, wten, out);
}